// Round 2
// baseline (735.156 us; speedup 1.0000x reference)
//
#include <hip/hip_runtime.h>

typedef unsigned short u16;
typedef __attribute__((ext_vector_type(8))) short short8;
typedef __attribute__((ext_vector_type(4))) float f32x4;

#define SHIFT_ 4

__device__ __forceinline__ float bf2f(u16 u) {
  unsigned x = ((unsigned)u) << 16;
  return __builtin_bit_cast(float, x);
}
__device__ __forceinline__ u16 f2bf(float f) {
  unsigned u = __builtin_bit_cast(unsigned, f);
  u += 0x7fffu + ((u >> 16) & 1u);
  return (u16)(u >> 16);
}
__device__ __forceinline__ short8 ld8(const u16* p) {
  return *(const short8*)p;
}
__device__ __forceinline__ void gld16(const void* g, void* l) {
  __builtin_amdgcn_global_load_lds(
      (const __attribute__((address_space(1))) unsigned int*)g,
      (__attribute__((address_space(3))) unsigned int*)l, 16, 0, 0);
}

// ---------------- transpose + fp32->bf16 convert (R x C fp32 -> C x R bf16) --
__global__ void transp(const float* __restrict__ in, u16* __restrict__ out, int R, int C) {
  __shared__ u16 t[32][33];
  int tx = threadIdx.x & 31, ty = threadIdx.x >> 5;
  int c0 = blockIdx.x * 32, r0 = blockIdx.y * 32;
#pragma unroll
  for (int i = 0; i < 4; i++)
    t[ty + i * 8][tx] = f2bf(in[(size_t)(r0 + ty + i * 8) * C + c0 + tx]);
  __syncthreads();
#pragma unroll
  for (int i = 0; i < 4; i++)
    out[(size_t)(c0 + ty + i * 8) * R + r0 + tx] = t[tx][ty + i * 8];
}

// ---------------- LayerNorm fp32 -> bf16 (optionally fused shift+window) -----
__global__ void ln_win(const float* __restrict__ hid, const float* __restrict__ g,
                       const float* __restrict__ b, u16* __restrict__ out, int windowed) {
  int wv = threadIdx.x >> 6, lane = threadIdx.x & 63;
  int tokid = blockIdx.x * 4 + wv;
  size_t src;
  if (windowed) {
    int t = tokid & 63, w = tokid >> 6;
    int winin = w & 63, bb = w >> 6;
    int r = ((winin >> 3) * 8 + (t >> 3) + SHIFT_) & 63;
    int c = ((winin & 7) * 8 + (t & 7) + SHIFT_) & 63;
    src = ((size_t)bb * 4096 + r * 64 + c) * 512;
  } else {
    src = (size_t)tokid * 512;
  }
  f32x4 x0 = *(const f32x4*)(hid + src + lane * 8);
  f32x4 x1 = *(const f32x4*)(hid + src + lane * 8 + 4);
  float x[8];
#pragma unroll
  for (int e = 0; e < 4; e++) { x[e] = x0[e]; x[e + 4] = x1[e]; }
  float s = 0.f, s2 = 0.f;
#pragma unroll
  for (int e = 0; e < 8; e++) {
    s += x[e];
    s2 += x[e] * x[e];
  }
#pragma unroll
  for (int m = 1; m < 64; m <<= 1) {
    s += __shfl_xor(s, m);
    s2 += __shfl_xor(s2, m);
  }
  float mean = s * (1.f / 512.f);
  float var = s2 * (1.f / 512.f) - mean * mean;
  float rstd = rsqrtf(var + 1e-5f);
  u16 pack[8];
#pragma unroll
  for (int e = 0; e < 8; e++) {
    int c = lane * 8 + e;
    float y = (x[e] - mean) * rstd * g[c] + b[c];
    pack[e] = f2bf(y);
  }
  *(short8*)(out + (size_t)tokid * 512 + lane * 8) = *(const short8*)pack;
}

// ---------------- GEMM: C = A(MxK) @ Bt^T + bias, Bt is (N x K) bf16 --------
// epi 0: outb = bf16(val)                        (out MxN, bf16)
// epi 1: window-reverse+unshift: outf[b,l,n] = resf[b,l,n] + val   (fp32)
// epi 2: outb = bf16(gelu(val))
// epi 3: outf[(row_off+m)*512+n] = resf[..] + val  (fp32, outf may alias resf)
__global__ __launch_bounds__(256) void gemm_bt(
    const u16* __restrict__ A, const u16* __restrict__ Bt,
    const float* __restrict__ bias, u16* __restrict__ outb, float* __restrict__ outf,
    const float* __restrict__ resf, int M, int N, int K, int epi, int row_off) {
  __shared__ __attribute__((aligned(16))) u16 As[4096];
  __shared__ __attribute__((aligned(16))) u16 Bs[4096];
  const int tid = threadIdx.x;
  const int wv = tid >> 6, lane = tid & 63;
  const int l15 = lane & 15, quad = lane >> 4;
  const int m0 = blockIdx.x * 128, n0 = blockIdx.y * 128;
  const int wm = (wv >> 1) * 64, wn = (wv & 1) * 64;

  const int srow = wv * 16 + (lane >> 2);
  const int scol = (lane & 3) * 8;
  const u16* ga0 = A + (size_t)(m0 + srow) * K + scol;
  const u16* ga1 = ga0 + (size_t)64 * K;
  const u16* gb0 = Bt + (size_t)(n0 + srow) * K + scol;
  const u16* gb1 = gb0 + (size_t)64 * K;
  u16* lA0 = As + wv * 512;
  u16* lA1 = As + 2048 + wv * 512;
  u16* lB0 = Bs + wv * 512;
  u16* lB1 = Bs + 2048 + wv * 512;

  f32x4 zero4 = {0.f, 0.f, 0.f, 0.f};
  f32x4 acc[4][4];
#pragma unroll
  for (int i = 0; i < 4; i++)
#pragma unroll
    for (int j = 0; j < 4; j++) acc[i][j] = zero4;

  const int kiter = K >> 5;
  for (int ko = 0; ko < kiter; ++ko) {
    __syncthreads();
    gld16(ga0, lA0);
    gld16(ga1, lA1);
    gld16(gb0, lB0);
    gld16(gb1, lB1);
    ga0 += 32; ga1 += 32; gb0 += 32; gb1 += 32;
    __syncthreads();
    short8 af[4], bfr[4];
#pragma unroll
    for (int mt = 0; mt < 4; mt++) af[mt] = ld8(As + (wm + mt * 16 + l15) * 32 + quad * 8);
#pragma unroll
    for (int nt = 0; nt < 4; nt++) bfr[nt] = ld8(Bs + (wn + nt * 16 + l15) * 32 + quad * 8);
#pragma unroll
    for (int mt = 0; mt < 4; mt++)
#pragma unroll
      for (int nt = 0; nt < 4; nt++)
        acc[mt][nt] = __builtin_amdgcn_mfma_f32_16x16x32_bf16(af[mt], bfr[nt], acc[mt][nt], 0, 0, 0);
  }

  float bvv[4];
#pragma unroll
  for (int nt = 0; nt < 4; nt++) bvv[nt] = bias[n0 + wn + nt * 16 + l15];

#pragma unroll
  for (int mt = 0; mt < 4; mt++) {
#pragma unroll
    for (int rr = 0; rr < 4; rr++) {
      int gm = m0 + wm + mt * 16 + quad * 4 + rr;
      size_t rowbase;
      if (epi == 1) {
        int tok = gm & 63, winin = (gm >> 6) & 63, bb = gm >> 12;
        int sr = (winin >> 3) * 8 + (tok >> 3);
        int sc = (winin & 7) * 8 + (tok & 7);
        int fr = (sr + SHIFT_) & 63, fc = (sc + SHIFT_) & 63;
        rowbase = ((size_t)bb * 4096 + fr * 64 + fc) * 512;
      } else if (epi == 3) {
        rowbase = (size_t)(row_off + gm) * 512;
      } else {
        rowbase = (size_t)gm * N;
      }
#pragma unroll
      for (int nt = 0; nt < 4; nt++) {
        int gn = n0 + wn + nt * 16 + l15;
        float val = acc[mt][nt][rr] + bvv[nt];
        if (epi == 0) {
          outb[rowbase + gn] = f2bf(val);
        } else if (epi == 2) {
          float gl = 0.5f * val * (1.0f + erff(val * 0.70710678118f));
          outb[rowbase + gn] = f2bf(gl);
        } else {
          size_t idx = rowbase + gn;
          outf[idx] = resf[idx] + val;
        }
      }
    }
  }
}

// ---------------- attention: one wave per (window, head) ----------------
__global__ __launch_bounds__(64) void attn(const u16* __restrict__ q, const u16* __restrict__ k,
                                           const u16* __restrict__ v, const float* __restrict__ tbl,
                                           u16* __restrict__ ctx) {
  __shared__ __attribute__((aligned(16))) u16 Pl[64 * 80];
  __shared__ float tb[225];
  const int win = blockIdx.x, h = blockIdx.y;
  const int lane = threadIdx.x;
  const int l15 = lane & 15, quad = lane >> 4;

  for (int idx = lane; idx < 225; idx += 64) tb[idx] = tbl[idx * 16 + h];

  const size_t base = ((size_t)win * 64) * 512 + h * 32;
  short8 aq[4], bkf[4];
#pragma unroll
  for (int mt = 0; mt < 4; mt++) aq[mt] = ld8(q + base + (size_t)(mt * 16 + l15) * 512 + quad * 8);
#pragma unroll
  for (int nt = 0; nt < 4; nt++) bkf[nt] = ld8(k + base + (size_t)(nt * 16 + l15) * 512 + quad * 8);

  f32x4 zero4 = {0.f, 0.f, 0.f, 0.f};
  f32x4 s[4][4];
#pragma unroll
  for (int i = 0; i < 4; i++)
#pragma unroll
    for (int j = 0; j < 4; j++) s[i][j] = zero4;
#pragma unroll
  for (int mt = 0; mt < 4; mt++)
#pragma unroll
    for (int nt = 0; nt < 4; nt++)
      s[mt][nt] = __builtin_amdgcn_mfma_f32_16x16x32_bf16(aq[mt], bkf[nt], s[mt][nt], 0, 0, 0);

  __syncthreads();  // tb ready

  const int winin = win & 63;
  const int wrow0 = (winin >> 3) * 8, wcol0 = (winin & 7) * 8;
  int valc[4], ci[4], cj[4];
#pragma unroll
  for (int nt = 0; nt < 4; nt++) {
    int ct = nt * 16 + l15;
    ci[nt] = ct >> 3;
    cj[nt] = ct & 7;
    int rr_ = wrow0 + ci[nt], cc_ = wcol0 + cj[nt];
    valc[nt] = 3 * (rr_ < 56 ? 0 : (rr_ < 60 ? 1 : 2)) + (cc_ < 56 ? 0 : (cc_ < 60 ? 1 : 2));
  }
  const float scale = 0.17677669529663687f;  // 1/sqrt(32)
#pragma unroll
  for (int mt = 0; mt < 4; mt++) {
#pragma unroll
    for (int rr = 0; rr < 4; rr++) {
      int rt = mt * 16 + quad * 4 + rr;
      int i1 = rt >> 3, j1 = rt & 7;
      int rrow = wrow0 + i1, rcol = wcol0 + j1;
      int valr = 3 * (rrow < 56 ? 0 : (rrow < 60 ? 1 : 2)) + (rcol < 56 ? 0 : (rcol < 60 ? 1 : 2));
      float sv[4];
      float mx = -1e30f;
#pragma unroll
      for (int nt = 0; nt < 4; nt++) {
        int idx = (i1 - ci[nt] + 7) * 15 + (j1 - cj[nt] + 7);
        float e = s[mt][nt][rr] * scale + tb[idx] + (valr == valc[nt] ? 0.f : -100.f);
        sv[nt] = e;
        mx = fmaxf(mx, e);
      }
#pragma unroll
      for (int m = 1; m < 16; m <<= 1) mx = fmaxf(mx, __shfl_xor(mx, m));
      float sum = 0.f;
#pragma unroll
      for (int nt = 0; nt < 4; nt++) {
        sv[nt] = __expf(sv[nt] - mx);
        sum += sv[nt];
      }
#pragma unroll
      for (int m = 1; m < 16; m <<= 1) sum += __shfl_xor(sum, m);
      float inv = 1.f / sum;
#pragma unroll
      for (int nt = 0; nt < 4; nt++) Pl[rt * 80 + nt * 16 + l15] = f2bf(sv[nt] * inv);
    }
  }
  __syncthreads();

  // O = P(64x64) @ V(64x32)
  f32x4 o[4][2];
#pragma unroll
  for (int i = 0; i < 4; i++)
#pragma unroll
    for (int j = 0; j < 2; j++) o[i][j] = zero4;
#pragma unroll
  for (int kk = 0; kk < 2; kk++) {
    short8 bv2[2];
#pragma unroll
    for (int nt = 0; nt < 2; nt++) {
      short8 t;
#pragma unroll
      for (int j = 0; j < 8; j++)
        t[j] = (short)v[base + (size_t)(kk * 32 + quad * 8 + j) * 512 + nt * 16 + l15];
      bv2[nt] = t;
    }
#pragma unroll
    for (int mt = 0; mt < 4; mt++) {
      short8 ap = ld8(Pl + (mt * 16 + l15) * 80 + kk * 32 + quad * 8);
#pragma unroll
      for (int nt = 0; nt < 2; nt++)
        o[mt][nt] = __builtin_amdgcn_mfma_f32_16x16x32_bf16(ap, bv2[nt], o[mt][nt], 0, 0, 0);
    }
  }
#pragma unroll
  for (int mt = 0; mt < 4; mt++)
#pragma unroll
    for (int rr = 0; rr < 4; rr++) {
      int rt = mt * 16 + quad * 4 + rr;
#pragma unroll
      for (int nt = 0; nt < 2; nt++)
        ctx[base + (size_t)rt * 512 + nt * 16 + l15] = f2bf(o[mt][nt][rr]);
    }
}

extern "C" void kernel_launch(void* const* d_in, const int* in_sizes, int n_in,
                              void* d_out, int out_size, void* d_ws, size_t ws_size,
                              hipStream_t stream) {
  const float* hs   = (const float*)d_in[0];
  const float* ln1g = (const float*)d_in[1];
  const float* ln1b = (const float*)d_in[2];
  const float* wq   = (const float*)d_in[3];
  const float* bq   = (const float*)d_in[4];
  const float* wk   = (const float*)d_in[5];
  const float* bk   = (const float*)d_in[6];
  const float* wvp  = (const float*)d_in[7];
  const float* bv   = (const float*)d_in[8];
  const float* tbl  = (const float*)d_in[9];
  const float* wo   = (const float*)d_in[10];
  const float* bo   = (const float*)d_in[11];
  const float* ln2g = (const float*)d_in[12];
  const float* ln2b = (const float*)d_in[13];
  const float* w1   = (const float*)d_in[14];
  const float* b1   = (const float*)d_in[15];
  const float* w2   = (const float*)d_in[16];
  const float* b2   = (const float*)d_in[17];
  float* out = (float*)d_out;
  u16* ws = (u16*)d_ws;

  const size_t S = (size_t)32768 * 512;
  u16* xw  = ws;           // LN1 windowed out (bf16); later reused as ctx
  u16* qb  = ws + S;       // Q (bf16); later reused as LN2 out
  u16* kb  = ws + 2 * S;   // K (bf16); later y1 chunk (spans kb..vb end, 2S u16)
  u16* vb  = ws + 3 * S;   // V (bf16)
  u16* wt  = ws + 4 * S;   // transposed weights (bf16)
  u16* wqT = wt;
  u16* wkT = wt + 262144;
  u16* wvT = wt + 524288;
  u16* woT = wt + 786432;
  u16* w1T = wt + 1048576;
  u16* w2T = wt + 2097152;
  float* hid = out;        // residual stream lives in d_out (fp32)

  transp<<<dim3(16, 16), 256, 0, stream>>>(wq, wqT, 512, 512);
  transp<<<dim3(16, 16), 256, 0, stream>>>(wk, wkT, 512, 512);
  transp<<<dim3(16, 16), 256, 0, stream>>>(wvp, wvT, 512, 512);
  transp<<<dim3(16, 16), 256, 0, stream>>>(wo, woT, 512, 512);
  transp<<<dim3(64, 16), 256, 0, stream>>>(w1, w1T, 512, 2048);
  transp<<<dim3(16, 64), 256, 0, stream>>>(w2, w2T, 2048, 512);

  ln_win<<<8192, 256, 0, stream>>>(hs, ln1g, ln1b, xw, 1);

  gemm_bt<<<dim3(256, 4), 256, 0, stream>>>(xw, wqT, bq, qb, nullptr, nullptr, 32768, 512, 512, 0, 0);
  gemm_bt<<<dim3(256, 4), 256, 0, stream>>>(xw, wkT, bk, kb, nullptr, nullptr, 32768, 512, 512, 0, 0);
  gemm_bt<<<dim3(256, 4), 256, 0, stream>>>(xw, wvT, bv, vb, nullptr, nullptr, 32768, 512, 512, 0, 0);

  attn<<<dim3(512, 16), 64, 0, stream>>>(qb, kb, vb, tbl, xw);

  // hid = hs + window_reverse(ctx @ Wo + bo)   (fp32, into d_out)
  gemm_bt<<<dim3(256, 4), 256, 0, stream>>>(xw, woT, bo, nullptr, hid, hs, 32768, 512, 512, 1, 0);

  // LN2(hid) -> qb (bf16)
  ln_win<<<8192, 256, 0, stream>>>(hid, ln2g, ln2b, qb, 0);

  for (int ch = 0; ch < 2; ++ch) {
    gemm_bt<<<dim3(128, 16), 256, 0, stream>>>(qb + (size_t)ch * 16384 * 512, w1T, b1, kb,
                                               nullptr, nullptr, 16384, 2048, 512, 2, 0);
    // out = hid + y1 @ w2T + b2  (fp32, in-place RMW on d_out)
    gemm_bt<<<dim3(128, 4), 256, 0, stream>>>(kb, w2T, b2, nullptr, out, hid, 16384, 512, 2048, 3,
                                              ch * 16384);
  }
}

// Round 3
// 666.029 us; speedup vs baseline: 1.1038x; 1.1038x over previous
//
#include <hip/hip_runtime.h>

typedef unsigned short u16;
typedef __attribute__((ext_vector_type(8))) short short8;
typedef __attribute__((ext_vector_type(4))) float f32x4;

#define SHIFT_ 4

__device__ __forceinline__ float bf2f(u16 u) {
  unsigned x = ((unsigned)u) << 16;
  return __builtin_bit_cast(float, x);
}
__device__ __forceinline__ u16 f2bf(float f) {
  unsigned u = __builtin_bit_cast(unsigned, f);
  u += 0x7fffu + ((u >> 16) & 1u);
  return (u16)(u >> 16);
}
__device__ __forceinline__ short8 ld8(const u16* p) {
  return *(const short8*)p;
}
__device__ __forceinline__ void gld16(const void* g, void* l) {
  __builtin_amdgcn_global_load_lds(
      (const __attribute__((address_space(1))) unsigned int*)g,
      (__attribute__((address_space(3))) unsigned int*)l, 16, 0, 0);
}
__device__ __forceinline__ float gelu_t(float x) {
  float u = 0.7978845608028654f * (x + 0.044715f * x * x * x);
  float e = __expf(-2.f * fabsf(u));
  float th = (1.f - e) / (1.f + e);
  th = u < 0.f ? -th : th;
  return 0.5f * x * (1.f + th);
}

// ---------------- transpose + fp32->bf16 convert (R x C fp32 -> C x R bf16) --
__global__ void transp(const float* __restrict__ in, u16* __restrict__ out, int R, int C) {
  __shared__ u16 t[32][33];
  int tx = threadIdx.x & 31, ty = threadIdx.x >> 5;
  int c0 = blockIdx.x * 32, r0 = blockIdx.y * 32;
#pragma unroll
  for (int i = 0; i < 4; i++)
    t[ty + i * 8][tx] = f2bf(in[(size_t)(r0 + ty + i * 8) * C + c0 + tx]);
  __syncthreads();
#pragma unroll
  for (int i = 0; i < 4; i++)
    out[(size_t)(c0 + ty + i * 8) * R + r0 + tx] = t[tx][ty + i * 8];
}

__global__ void concat_bias(const float* __restrict__ a, const float* __restrict__ b,
                            const float* __restrict__ c, float* __restrict__ o) {
  int i = blockIdx.x * 256 + threadIdx.x;
  if (i < 512) o[i] = a[i];
  else if (i < 1024) o[i] = b[i - 512];
  else if (i < 1536) o[i] = c[i - 1024];
}

// ---------------- LayerNorm fp32 -> bf16 (optionally fused shift+window) -----
__global__ void ln_win(const float* __restrict__ hid, const float* __restrict__ g,
                       const float* __restrict__ b, u16* __restrict__ out, int windowed) {
  int wv = threadIdx.x >> 6, lane = threadIdx.x & 63;
  int tokid = blockIdx.x * 4 + wv;
  size_t src;
  if (windowed) {
    int t = tokid & 63, w = tokid >> 6;
    int winin = w & 63, bb = w >> 6;
    int r = ((winin >> 3) * 8 + (t >> 3) + SHIFT_) & 63;
    int c = ((winin & 7) * 8 + (t & 7) + SHIFT_) & 63;
    src = ((size_t)bb * 4096 + r * 64 + c) * 512;
  } else {
    src = (size_t)tokid * 512;
  }
  f32x4 x0 = *(const f32x4*)(hid + src + lane * 8);
  f32x4 x1 = *(const f32x4*)(hid + src + lane * 8 + 4);
  float x[8];
#pragma unroll
  for (int e = 0; e < 4; e++) { x[e] = x0[e]; x[e + 4] = x1[e]; }
  float s = 0.f, s2 = 0.f;
#pragma unroll
  for (int e = 0; e < 8; e++) {
    s += x[e];
    s2 += x[e] * x[e];
  }
#pragma unroll
  for (int m = 1; m < 64; m <<= 1) {
    s += __shfl_xor(s, m);
    s2 += __shfl_xor(s2, m);
  }
  float mean = s * (1.f / 512.f);
  float var = s2 * (1.f / 512.f) - mean * mean;
  float rstd = rsqrtf(var + 1e-5f);
  u16 pack[8];
#pragma unroll
  for (int e = 0; e < 8; e++) {
    int c = lane * 8 + e;
    float y = (x[e] - mean) * rstd * g[c] + b[c];
    pack[e] = f2bf(y);
  }
  *(short8*)(out + (size_t)tokid * 512 + lane * 8) = *(const short8*)pack;
}

// ---------------- GEMM: C = A(MxK) @ Bt^T + bias, Bt is (N x K) bf16 --------
// Tile: BM x 128, BM*2 threads (BM/32 waves, each 64x64).
// epi 0: outb = bf16(val)
// epi 1: window-reverse+unshift: outf[b,l,n] = resf[b,l,n] + val   (fp32)
// epi 2: outb = bf16(gelu(val))
// epi 3: outf[(row_off+m)*512+n] = resf[..] + val  (fp32, outf may alias resf)
template <int BM>
__global__ __launch_bounds__(BM * 2) void gemm_bt(
    const u16* __restrict__ A, const u16* __restrict__ Bt,
    const float* __restrict__ bias, u16* __restrict__ outb, float* __restrict__ outf,
    const float* __restrict__ resf, int M, int N, int K, int epi, int row_off) {
  __shared__ __attribute__((aligned(16))) u16 As[BM * 32];
  __shared__ __attribute__((aligned(16))) u16 Bs[4096];
  const int tid = threadIdx.x;
  const int wv = tid >> 6, lane = tid & 63;
  const int l15 = lane & 15, quad = lane >> 4;
  const int m0 = blockIdx.x * BM, n0 = blockIdx.y * 128;
  const int wm = (wv >> 1) * 64, wn = (wv & 1) * 64;

  const int arow = tid >> 2;          // 0..BM/2-1 (BM=128) or 0..127 (BM=256)
  const int acol = (tid & 3) * 8;
  const u16* ga0 = A + (size_t)(m0 + arow) * K + acol;
  const u16* ga1 = ga0 + (size_t)(BM / 2) * K;
  u16* lA0 = As + tid * 8;
  u16* lA1 = As + BM * 16 + tid * 8;
  const u16* gb0 = Bt + (size_t)(n0 + arow) * K + acol;
  u16* lB0 = Bs + tid * 8;
  const u16* gb1;
  u16* lB1;
  if (BM == 128) {  // 256 threads: B tile needs two rounds
    gb1 = gb0 + (size_t)64 * K;
    lB1 = Bs + 2048 + tid * 8;
  }

  f32x4 zero4 = {0.f, 0.f, 0.f, 0.f};
  f32x4 acc[4][4];
#pragma unroll
  for (int i = 0; i < 4; i++)
#pragma unroll
    for (int j = 0; j < 4; j++) acc[i][j] = zero4;

  const int kiter = K >> 5;
  for (int ko = 0; ko < kiter; ++ko) {
    __syncthreads();
    gld16(ga0, lA0);
    gld16(ga1, lA1);
    gld16(gb0, lB0);
    if (BM == 128) gld16(gb1, lB1);
    ga0 += 32; ga1 += 32; gb0 += 32;
    if (BM == 128) gb1 += 32;
    __syncthreads();
    short8 af[4], bfr[4];
#pragma unroll
    for (int mt = 0; mt < 4; mt++) af[mt] = ld8(As + (wm + mt * 16 + l15) * 32 + quad * 8);
#pragma unroll
    for (int nt = 0; nt < 4; nt++) bfr[nt] = ld8(Bs + (wn + nt * 16 + l15) * 32 + quad * 8);
#pragma unroll
    for (int mt = 0; mt < 4; mt++)
#pragma unroll
      for (int nt = 0; nt < 4; nt++)
        acc[mt][nt] = __builtin_amdgcn_mfma_f32_16x16x32_bf16(af[mt], bfr[nt], acc[mt][nt], 0, 0, 0);
  }

  float bvv[4];
#pragma unroll
  for (int nt = 0; nt < 4; nt++) bvv[nt] = bias[n0 + wn + nt * 16 + l15];

#pragma unroll
  for (int mt = 0; mt < 4; mt++) {
#pragma unroll
    for (int rr = 0; rr < 4; rr++) {
      int gm = m0 + wm + mt * 16 + quad * 4 + rr;
      size_t rowbase;
      if (epi == 1) {
        int tok = gm & 63, winin = (gm >> 6) & 63, bb = gm >> 12;
        int sr = (winin >> 3) * 8 + (tok >> 3);
        int sc = (winin & 7) * 8 + (tok & 7);
        int fr = (sr + SHIFT_) & 63, fc = (sc + SHIFT_) & 63;
        rowbase = ((size_t)bb * 4096 + fr * 64 + fc) * 512;
      } else if (epi == 3) {
        rowbase = (size_t)(row_off + gm) * 512;
      } else {
        rowbase = (size_t)gm * N;
      }
#pragma unroll
      for (int nt = 0; nt < 4; nt++) {
        int gn = n0 + wn + nt * 16 + l15;
        float val = acc[mt][nt][rr] + bvv[nt];
        if (epi == 0) {
          outb[rowbase + gn] = f2bf(val);
        } else if (epi == 2) {
          outb[rowbase + gn] = f2bf(gelu_t(val));
        } else {
          size_t idx = rowbase + gn;
          outf[idx] = resf[idx] + val;
        }
      }
    }
  }
}

// ---------------- attention: one wave per (window, head) ----------------
// qkv: (32768 x 1536) bf16, row = token, cols [h*32 | +512 k | +1024 v]
__global__ __launch_bounds__(64) void attn(const u16* __restrict__ qkv,
                                           const float* __restrict__ tbl,
                                           u16* __restrict__ ctx) {
  __shared__ __attribute__((aligned(16))) u16 Pl[64 * 80];
  __shared__ float tb[225];
  const int win = blockIdx.x, h = blockIdx.y;
  const int lane = threadIdx.x;
  const int l15 = lane & 15, quad = lane >> 4;

  for (int idx = lane; idx < 225; idx += 64) tb[idx] = tbl[idx * 16 + h];

  const size_t qbase = (size_t)win * 64 * 1536 + h * 32;
  short8 aq[4], bkf[4];
#pragma unroll
  for (int mt = 0; mt < 4; mt++)
    aq[mt] = ld8(qkv + qbase + (size_t)(mt * 16 + l15) * 1536 + quad * 8);
#pragma unroll
  for (int nt = 0; nt < 4; nt++)
    bkf[nt] = ld8(qkv + qbase + 512 + (size_t)(nt * 16 + l15) * 1536 + quad * 8);

  f32x4 zero4 = {0.f, 0.f, 0.f, 0.f};
  f32x4 s[4][4];
#pragma unroll
  for (int i = 0; i < 4; i++)
#pragma unroll
    for (int j = 0; j < 4; j++) s[i][j] = zero4;
#pragma unroll
  for (int mt = 0; mt < 4; mt++)
#pragma unroll
    for (int nt = 0; nt < 4; nt++)
      s[mt][nt] = __builtin_amdgcn_mfma_f32_16x16x32_bf16(aq[mt], bkf[nt], s[mt][nt], 0, 0, 0);

  __syncthreads();  // tb ready

  const int winin = win & 63;
  const int wrow0 = (winin >> 3) * 8, wcol0 = (winin & 7) * 8;
  int valc[4], ci[4], cj[4];
#pragma unroll
  for (int nt = 0; nt < 4; nt++) {
    int ct = nt * 16 + l15;
    ci[nt] = ct >> 3;
    cj[nt] = ct & 7;
    int rr_ = wrow0 + ci[nt], cc_ = wcol0 + cj[nt];
    valc[nt] = 3 * (rr_ < 56 ? 0 : (rr_ < 60 ? 1 : 2)) + (cc_ < 56 ? 0 : (cc_ < 60 ? 1 : 2));
  }
  const float scale = 0.17677669529663687f;  // 1/sqrt(32)
#pragma unroll
  for (int mt = 0; mt < 4; mt++) {
#pragma unroll
    for (int rr = 0; rr < 4; rr++) {
      int rt = mt * 16 + quad * 4 + rr;
      int i1 = rt >> 3, j1 = rt & 7;
      int rrow = wrow0 + i1, rcol = wcol0 + j1;
      int valr = 3 * (rrow < 56 ? 0 : (rrow < 60 ? 1 : 2)) + (rcol < 56 ? 0 : (rcol < 60 ? 1 : 2));
      float sv[4];
      float mx = -1e30f;
#pragma unroll
      for (int nt = 0; nt < 4; nt++) {
        int idx = (i1 - ci[nt] + 7) * 15 + (j1 - cj[nt] + 7);
        float e = s[mt][nt][rr] * scale + tb[idx] + (valr == valc[nt] ? 0.f : -100.f);
        sv[nt] = e;
        mx = fmaxf(mx, e);
      }
#pragma unroll
      for (int m = 1; m < 16; m <<= 1) mx = fmaxf(mx, __shfl_xor(mx, m));
      float sum = 0.f;
#pragma unroll
      for (int nt = 0; nt < 4; nt++) {
        sv[nt] = __expf(sv[nt] - mx);
        sum += sv[nt];
      }
#pragma unroll
      for (int m = 1; m < 16; m <<= 1) sum += __shfl_xor(sum, m);
      float inv = 1.f / sum;
#pragma unroll
      for (int nt = 0; nt < 4; nt++) Pl[rt * 80 + nt * 16 + l15] = f2bf(sv[nt] * inv);
    }
  }
  __syncthreads();

  // O = P(64x64) @ V(64x32)
  const size_t vbase = (size_t)win * 64 * 1536 + 1024 + h * 32;
  f32x4 o[4][2];
#pragma unroll
  for (int i = 0; i < 4; i++)
#pragma unroll
    for (int j = 0; j < 2; j++) o[i][j] = zero4;
#pragma unroll
  for (int kk = 0; kk < 2; kk++) {
    short8 bv2[2];
#pragma unroll
    for (int nt = 0; nt < 2; nt++) {
      short8 t;
#pragma unroll
      for (int j = 0; j < 8; j++)
        t[j] = (short)qkv[vbase + (size_t)(kk * 32 + quad * 8 + j) * 1536 + nt * 16 + l15];
      bv2[nt] = t;
    }
#pragma unroll
    for (int mt = 0; mt < 4; mt++) {
      short8 ap = ld8(Pl + (mt * 16 + l15) * 80 + kk * 32 + quad * 8);
#pragma unroll
      for (int nt = 0; nt < 2; nt++)
        o[mt][nt] = __builtin_amdgcn_mfma_f32_16x16x32_bf16(ap, bv2[nt], o[mt][nt], 0, 0, 0);
    }
  }
  const size_t cbase = (size_t)win * 64 * 512 + h * 32;
#pragma unroll
  for (int mt = 0; mt < 4; mt++)
#pragma unroll
    for (int rr = 0; rr < 4; rr++) {
      int rt = mt * 16 + quad * 4 + rr;
#pragma unroll
      for (int nt = 0; nt < 2; nt++)
        ctx[cbase + (size_t)rt * 512 + nt * 16 + l15] = f2bf(o[mt][nt][rr]);
    }
}

extern "C" void kernel_launch(void* const* d_in, const int* in_sizes, int n_in,
                              void* d_out, int out_size, void* d_ws, size_t ws_size,
                              hipStream_t stream) {
  const float* hs   = (const float*)d_in[0];
  const float* ln1g = (const float*)d_in[1];
  const float* ln1b = (const float*)d_in[2];
  const float* wq   = (const float*)d_in[3];
  const float* bq   = (const float*)d_in[4];
  const float* wk   = (const float*)d_in[5];
  const float* bk   = (const float*)d_in[6];
  const float* wvp  = (const float*)d_in[7];
  const float* bv   = (const float*)d_in[8];
  const float* tbl  = (const float*)d_in[9];
  const float* wo   = (const float*)d_in[10];
  const float* bo   = (const float*)d_in[11];
  const float* ln2g = (const float*)d_in[12];
  const float* ln2b = (const float*)d_in[13];
  const float* w1   = (const float*)d_in[14];
  const float* b1   = (const float*)d_in[15];
  const float* w2   = (const float*)d_in[16];
  const float* b2   = (const float*)d_in[17];
  float* out = (float*)d_out;
  u16* ws = (u16*)d_ws;

  const size_t S = (size_t)32768 * 512;
  u16* xw   = ws;          // LN1 windowed out (bf16); later ctx
  u16* qkv  = ws + S;      // fused QKV out (32768 x 1536 bf16), spans 3S
  u16* qb   = ws + S;      // after attn: reused as LN2 out (S)
  u16* kb   = ws + 2 * S;  // after attn: y1 chunk (2S u16)
  u16* wt   = ws + 4 * S;  // transposed weights (bf16)
  u16* wqkvT = wt;         // 1536 x 512 (wq^T | wk^T | wv^T rows)
  u16* woT  = wt + 786432;
  u16* w1T  = wt + 1048576;
  u16* w2T  = wt + 2097152;
  float* bcat = (float*)(wt + 3145728);  // 1536 fp32
  float* hid = out;        // residual stream lives in d_out (fp32)

  transp<<<dim3(16, 16), 256, 0, stream>>>(wq, wqkvT, 512, 512);
  transp<<<dim3(16, 16), 256, 0, stream>>>(wk, wqkvT + 262144, 512, 512);
  transp<<<dim3(16, 16), 256, 0, stream>>>(wvp, wqkvT + 524288, 512, 512);
  transp<<<dim3(16, 16), 256, 0, stream>>>(wo, woT, 512, 512);
  transp<<<dim3(64, 16), 256, 0, stream>>>(w1, w1T, 512, 2048);
  transp<<<dim3(16, 64), 256, 0, stream>>>(w2, w2T, 2048, 512);
  concat_bias<<<6, 256, 0, stream>>>(bq, bk, bv, bcat);

  ln_win<<<8192, 256, 0, stream>>>(hs, ln1g, ln1b, xw, 1);

  // fused QKV: (32768 x 512) @ (512 x 1536) -> qkv
  gemm_bt<256><<<dim3(128, 12), 512, 0, stream>>>(xw, wqkvT, bcat, qkv, nullptr, nullptr,
                                                  32768, 1536, 512, 0, 0);

  attn<<<dim3(512, 16), 64, 0, stream>>>(qkv, tbl, xw);

  // hid = hs + window_reverse(ctx @ Wo + bo)   (fp32, into d_out)
  gemm_bt<256><<<dim3(128, 4), 512, 0, stream>>>(xw, woT, bo, nullptr, hid, hs,
                                                 32768, 512, 512, 1, 0);

  // LN2(hid) -> qb (bf16)
  ln_win<<<8192, 256, 0, stream>>>(hid, ln2g, ln2b, qb, 0);

  for (int ch = 0; ch < 2; ++ch) {
    gemm_bt<256><<<dim3(64, 16), 512, 0, stream>>>(qb + (size_t)ch * 16384 * 512, w1T, b1, kb,
                                                   nullptr, nullptr, 16384, 2048, 512, 2, 0);
    // out = hid + y1 @ w2T + b2  (fp32, in-place RMW on d_out)
    gemm_bt<128><<<dim3(128, 4), 256, 0, stream>>>(kb, w2T, b2, nullptr, out, hid,
                                                   16384, 512, 2048, 3, ch * 16384);
  }
}

// Round 4
// 651.270 us; speedup vs baseline: 1.1288x; 1.0227x over previous
//
#include <hip/hip_runtime.h>

typedef unsigned short u16;
typedef __attribute__((ext_vector_type(8))) short short8;
typedef __attribute__((ext_vector_type(4))) float f32x4;

#define SHIFT_ 4

__device__ __forceinline__ float bf2f(u16 u) {
  unsigned x = ((unsigned)u) << 16;
  return __builtin_bit_cast(float, x);
}
__device__ __forceinline__ u16 f2bf(float f) {
  unsigned u = __builtin_bit_cast(unsigned, f);
  u += 0x7fffu + ((u >> 16) & 1u);
  return (u16)(u >> 16);
}
__device__ __forceinline__ short8 ld8(const u16* p) {
  return *(const short8*)p;
}
__device__ __forceinline__ void gld16(const void* g, void* l) {
  __builtin_amdgcn_global_load_lds(
      (const __attribute__((address_space(1))) unsigned int*)g,
      (__attribute__((address_space(3))) unsigned int*)l, 16, 0, 0);
}
__device__ __forceinline__ float gelu_t(float x) {
  float u = 0.7978845608028654f * (x + 0.044715f * x * x * x);
  float e = __expf(-2.f * fabsf(u));
  float th = (1.f - e) / (1.f + e);
  th = u < 0.f ? -th : th;
  return 0.5f * x * (1.f + th);
}

// ---------------- transpose + fp32->bf16 convert (R x C fp32 -> C x R bf16) --
__global__ void transp(const float* __restrict__ in, u16* __restrict__ out, int R, int C) {
  __shared__ u16 t[32][33];
  int tx = threadIdx.x & 31, ty = threadIdx.x >> 5;
  int c0 = blockIdx.x * 32, r0 = blockIdx.y * 32;
#pragma unroll
  for (int i = 0; i < 4; i++)
    t[ty + i * 8][tx] = f2bf(in[(size_t)(r0 + ty + i * 8) * C + c0 + tx]);
  __syncthreads();
#pragma unroll
  for (int i = 0; i < 4; i++)
    out[(size_t)(c0 + ty + i * 8) * R + r0 + tx] = t[tx][ty + i * 8];
}

__global__ void concat_bias(const float* __restrict__ a, const float* __restrict__ b,
                            const float* __restrict__ c, float* __restrict__ o) {
  int i = blockIdx.x * 256 + threadIdx.x;
  if (i < 512) o[i] = a[i];
  else if (i < 1024) o[i] = b[i - 512];
  else if (i < 1536) o[i] = c[i - 1024];
}

// ---------------- LayerNorm fp32 -> bf16 (optionally fused shift+window) -----
__global__ void ln_win(const float* __restrict__ hid, const float* __restrict__ g,
                       const float* __restrict__ b, u16* __restrict__ out, int windowed) {
  int wv = threadIdx.x >> 6, lane = threadIdx.x & 63;
  int tokid = blockIdx.x * 4 + wv;
  size_t src;
  if (windowed) {
    int t = tokid & 63, w = tokid >> 6;
    int winin = w & 63, bb = w >> 6;
    int r = ((winin >> 3) * 8 + (t >> 3) + SHIFT_) & 63;
    int c = ((winin & 7) * 8 + (t & 7) + SHIFT_) & 63;
    src = ((size_t)bb * 4096 + r * 64 + c) * 512;
  } else {
    src = (size_t)tokid * 512;
  }
  f32x4 x0 = *(const f32x4*)(hid + src + lane * 8);
  f32x4 x1 = *(const f32x4*)(hid + src + lane * 8 + 4);
  float x[8];
#pragma unroll
  for (int e = 0; e < 4; e++) { x[e] = x0[e]; x[e + 4] = x1[e]; }
  float s = 0.f, s2 = 0.f;
#pragma unroll
  for (int e = 0; e < 8; e++) {
    s += x[e];
    s2 += x[e] * x[e];
  }
#pragma unroll
  for (int m = 1; m < 64; m <<= 1) {
    s += __shfl_xor(s, m);
    s2 += __shfl_xor(s2, m);
  }
  float mean = s * (1.f / 512.f);
  float var = s2 * (1.f / 512.f) - mean * mean;
  float rstd = rsqrtf(var + 1e-5f);
  u16 pack[8];
#pragma unroll
  for (int e = 0; e < 8; e++) {
    int c = lane * 8 + e;
    float y = (x[e] - mean) * rstd * g[c] + b[c];
    pack[e] = f2bf(y);
  }
  *(short8*)(out + (size_t)tokid * 512 + lane * 8) = *(const short8*)pack;
}

// ---------------- GEMM: C = A(MxK) @ Bt^T + bias, Bt is (N x K) bf16 --------
// Tile: BM x 128 x BK=64, BM*2 threads. Each wave: 64x64 out.
// epi 0: outb = bf16(val)
// epi 1: window-reverse+unshift: outf[b,l,n] = resf[b,l,n] + val   (fp32)
// epi 2: outb = bf16(gelu(val))
// epi 3: outf[(row_off+m)*512+n] = resf[..] + val  (fp32, outf may alias resf)
template <int BM>
__global__ __launch_bounds__(BM * 2) void gemm_bt(
    const u16* __restrict__ A, const u16* __restrict__ Bt,
    const float* __restrict__ bias, u16* __restrict__ outb, float* __restrict__ outf,
    const float* __restrict__ resf, int M, int N, int K, int epi, int row_off) {
  constexpr int T = BM * 2;
  __shared__ __attribute__((aligned(16))) u16 As[BM * 64];
  __shared__ __attribute__((aligned(16))) u16 Bs[128 * 64];
  const int tid = threadIdx.x;
  const int wv = tid >> 6, lane = tid & 63;
  const int l15 = lane & 15, quad = lane >> 4;
  const int m0 = blockIdx.x * BM, n0 = blockIdx.y * 128;
  const int wm = (wv >> 1) * 64, wn = (wv & 1) * 64;

  const int arow = tid >> 3;          // 0..T/8-1
  const int acol = (tid & 7) * 8;
  const u16* gA = A + (size_t)(m0 + arow) * K + acol;
  const u16* gB = Bt + (size_t)(n0 + arow) * K + acol;
  u16* lA = As + arow * 64 + (tid & 7) * 8;
  u16* lB = Bs + arow * 64 + (tid & 7) * 8;

  f32x4 zero4 = {0.f, 0.f, 0.f, 0.f};
  f32x4 acc[4][4];
#pragma unroll
  for (int i = 0; i < 4; i++)
#pragma unroll
    for (int j = 0; j < 4; j++) acc[i][j] = zero4;

  const int kiter = K >> 6;
  for (int ko = 0; ko < kiter; ++ko) {
    __syncthreads();
#pragma unroll
    for (int r = 0; r < BM; r += T / 8) gld16(gA + (size_t)r * K, lA + r * 64);
#pragma unroll
    for (int r = 0; r < 128; r += T / 8) gld16(gB + (size_t)r * K, lB + r * 64);
    gA += 64;
    gB += 64;
    __syncthreads();
#pragma unroll
    for (int kk = 0; kk < 2; kk++) {
      short8 af[4], bfr[4];
#pragma unroll
      for (int mt = 0; mt < 4; mt++)
        af[mt] = ld8(As + (wm + mt * 16 + l15) * 64 + kk * 32 + quad * 8);
#pragma unroll
      for (int nt = 0; nt < 4; nt++)
        bfr[nt] = ld8(Bs + (wn + nt * 16 + l15) * 64 + kk * 32 + quad * 8);
#pragma unroll
      for (int mt = 0; mt < 4; mt++)
#pragma unroll
        for (int nt = 0; nt < 4; nt++)
          acc[mt][nt] = __builtin_amdgcn_mfma_f32_16x16x32_bf16(af[mt], bfr[nt], acc[mt][nt], 0, 0, 0);
    }
  }

  float bvv[4];
#pragma unroll
  for (int nt = 0; nt < 4; nt++) bvv[nt] = bias[n0 + wn + nt * 16 + l15];

#pragma unroll
  for (int mt = 0; mt < 4; mt++) {
#pragma unroll
    for (int rr = 0; rr < 4; rr++) {
      int gm = m0 + wm + mt * 16 + quad * 4 + rr;
      size_t rowbase;
      if (epi == 1) {
        int tok = gm & 63, winin = (gm >> 6) & 63, bb = gm >> 12;
        int sr = (winin >> 3) * 8 + (tok >> 3);
        int sc = (winin & 7) * 8 + (tok & 7);
        int fr = (sr + SHIFT_) & 63, fc = (sc + SHIFT_) & 63;
        rowbase = ((size_t)bb * 4096 + fr * 64 + fc) * 512;
      } else if (epi == 3) {
        rowbase = (size_t)(row_off + gm) * 512;
      } else {
        rowbase = (size_t)gm * N;
      }
#pragma unroll
      for (int nt = 0; nt < 4; nt++) {
        int gn = n0 + wn + nt * 16 + l15;
        float val = acc[mt][nt][rr] + bvv[nt];
        if (epi == 0) {
          outb[rowbase + gn] = f2bf(val);
        } else if (epi == 2) {
          outb[rowbase + gn] = f2bf(gelu_t(val));
        } else {
          size_t idx = rowbase + gn;
          outf[idx] = resf[idx] + val;
        }
      }
    }
  }
}

// ---------------- attention: one wave per (window, head) ----------------
// qkv: (32768 x 1536) bf16, row = token, cols [h*32 | +512 k | +1024 v]
__global__ __launch_bounds__(64) void attn(const u16* __restrict__ qkv,
                                           const float* __restrict__ tbl,
                                           u16* __restrict__ ctx) {
  __shared__ __attribute__((aligned(16))) u16 Pl[64 * 80];
  __shared__ __attribute__((aligned(16))) u16 Vt[32 * 72];  // V^T: [dim][token]
  __shared__ float tb[225];
  const int win = blockIdx.x, h = blockIdx.y;
  const int lane = threadIdx.x;
  const int l15 = lane & 15, quad = lane >> 4;

  for (int idx = lane; idx < 225; idx += 64) tb[idx] = tbl[idx * 16 + h];

  const size_t qbase = (size_t)win * 64 * 1536 + h * 32;
  const size_t vbase = qbase + 1024;

  // stage V transposed via coalesced b128 loads
#pragma unroll
  for (int rnd = 0; rnd < 4; rnd++) {
    int t = rnd * 16 + (lane >> 2);
    int c = (lane & 3) * 8;
    short8 vrow = ld8(qkv + vbase + (size_t)t * 1536 + c);
#pragma unroll
    for (int j = 0; j < 8; j++) Vt[(c + j) * 72 + t] = (u16)vrow[j];
  }

  short8 aq[4], bkf[4];
#pragma unroll
  for (int mt = 0; mt < 4; mt++)
    aq[mt] = ld8(qkv + qbase + (size_t)(mt * 16 + l15) * 1536 + quad * 8);
#pragma unroll
  for (int nt = 0; nt < 4; nt++)
    bkf[nt] = ld8(qkv + qbase + 512 + (size_t)(nt * 16 + l15) * 1536 + quad * 8);

  f32x4 zero4 = {0.f, 0.f, 0.f, 0.f};
  f32x4 s[4][4];
#pragma unroll
  for (int i = 0; i < 4; i++)
#pragma unroll
    for (int j = 0; j < 4; j++) s[i][j] = zero4;
#pragma unroll
  for (int mt = 0; mt < 4; mt++)
#pragma unroll
    for (int nt = 0; nt < 4; nt++)
      s[mt][nt] = __builtin_amdgcn_mfma_f32_16x16x32_bf16(aq[mt], bkf[nt], s[mt][nt], 0, 0, 0);

  __syncthreads();  // tb ready

  const int winin = win & 63;
  const int wrow0 = (winin >> 3) * 8, wcol0 = (winin & 7) * 8;
  int valc[4], ci[4], cj[4];
#pragma unroll
  for (int nt = 0; nt < 4; nt++) {
    int ct = nt * 16 + l15;
    ci[nt] = ct >> 3;
    cj[nt] = ct & 7;
    int rr_ = wrow0 + ci[nt], cc_ = wcol0 + cj[nt];
    valc[nt] = 3 * (rr_ < 56 ? 0 : (rr_ < 60 ? 1 : 2)) + (cc_ < 56 ? 0 : (cc_ < 60 ? 1 : 2));
  }
  const float scale = 0.17677669529663687f;  // 1/sqrt(32)
#pragma unroll
  for (int mt = 0; mt < 4; mt++) {
#pragma unroll
    for (int rr = 0; rr < 4; rr++) {
      int rt = mt * 16 + quad * 4 + rr;
      int i1 = rt >> 3, j1 = rt & 7;
      int rrow = wrow0 + i1, rcol = wcol0 + j1;
      int valr = 3 * (rrow < 56 ? 0 : (rrow < 60 ? 1 : 2)) + (rcol < 56 ? 0 : (rcol < 60 ? 1 : 2));
      float sv[4];
      float sum = 0.f;
      // scores are O(+-10): exp without max-subtraction is safe in fp32
#pragma unroll
      for (int nt = 0; nt < 4; nt++) {
        int idx = (i1 - ci[nt] + 7) * 15 + (j1 - cj[nt] + 7);
        float e = s[mt][nt][rr] * scale + tb[idx] + (valr == valc[nt] ? 0.f : -100.f);
        sv[nt] = __expf(e);
        sum += sv[nt];
      }
#pragma unroll
      for (int m = 1; m < 16; m <<= 1) sum += __shfl_xor(sum, m);
      float inv = 1.f / sum;
#pragma unroll
      for (int nt = 0; nt < 4; nt++) Pl[rt * 80 + nt * 16 + l15] = f2bf(sv[nt] * inv);
    }
  }
  __syncthreads();

  // O = P(64x64) @ V(64x32), V^T from LDS
  f32x4 o[4][2];
#pragma unroll
  for (int i = 0; i < 4; i++)
#pragma unroll
    for (int j = 0; j < 2; j++) o[i][j] = zero4;
#pragma unroll
  for (int kk = 0; kk < 2; kk++) {
    short8 bv2[2];
#pragma unroll
    for (int nt = 0; nt < 2; nt++)
      bv2[nt] = ld8(Vt + (nt * 16 + l15) * 72 + kk * 32 + quad * 8);
#pragma unroll
    for (int mt = 0; mt < 4; mt++) {
      short8 ap = ld8(Pl + (mt * 16 + l15) * 80 + kk * 32 + quad * 8);
#pragma unroll
      for (int nt = 0; nt < 2; nt++)
        o[mt][nt] = __builtin_amdgcn_mfma_f32_16x16x32_bf16(ap, bv2[nt], o[mt][nt], 0, 0, 0);
    }
  }
  const size_t cbase = (size_t)win * 64 * 512 + h * 32;
#pragma unroll
  for (int mt = 0; mt < 4; mt++)
#pragma unroll
    for (int rr = 0; rr < 4; rr++) {
      int rt = mt * 16 + quad * 4 + rr;
#pragma unroll
      for (int nt = 0; nt < 2; nt++)
        ctx[cbase + (size_t)rt * 512 + nt * 16 + l15] = f2bf(o[mt][nt][rr]);
    }
}

extern "C" void kernel_launch(void* const* d_in, const int* in_sizes, int n_in,
                              void* d_out, int out_size, void* d_ws, size_t ws_size,
                              hipStream_t stream) {
  const float* hs   = (const float*)d_in[0];
  const float* ln1g = (const float*)d_in[1];
  const float* ln1b = (const float*)d_in[2];
  const float* wq   = (const float*)d_in[3];
  const float* bq   = (const float*)d_in[4];
  const float* wk   = (const float*)d_in[5];
  const float* bk   = (const float*)d_in[6];
  const float* wvp  = (const float*)d_in[7];
  const float* bv   = (const float*)d_in[8];
  const float* tbl  = (const float*)d_in[9];
  const float* wo   = (const float*)d_in[10];
  const float* bo   = (const float*)d_in[11];
  const float* ln2g = (const float*)d_in[12];
  const float* ln2b = (const float*)d_in[13];
  const float* w1   = (const float*)d_in[14];
  const float* b1   = (const float*)d_in[15];
  const float* w2   = (const float*)d_in[16];
  const float* b2   = (const float*)d_in[17];
  float* out = (float*)d_out;
  u16* ws = (u16*)d_ws;

  const size_t S = (size_t)32768 * 512;
  u16* xw   = ws;          // LN1 windowed out (bf16); later ctx
  u16* qkv  = ws + S;      // fused QKV out (32768 x 1536 bf16), spans 3S
  u16* qb   = ws + S;      // after attn: reused as LN2 out (S)
  u16* kb   = ws + 2 * S;  // after attn: y1 chunk (2S u16)
  u16* wt   = ws + 4 * S;  // transposed weights (bf16)
  u16* wqkvT = wt;         // 1536 x 512 (wq^T | wk^T | wv^T rows)
  u16* woT  = wt + 786432;
  u16* w1T  = wt + 1048576;
  u16* w2T  = wt + 2097152;
  float* bcat = (float*)(wt + 3145728);  // 1536 fp32
  float* hid = out;        // residual stream lives in d_out (fp32)

  transp<<<dim3(16, 16), 256, 0, stream>>>(wq, wqkvT, 512, 512);
  transp<<<dim3(16, 16), 256, 0, stream>>>(wk, wqkvT + 262144, 512, 512);
  transp<<<dim3(16, 16), 256, 0, stream>>>(wvp, wqkvT + 524288, 512, 512);
  transp<<<dim3(16, 16), 256, 0, stream>>>(wo, woT, 512, 512);
  transp<<<dim3(64, 16), 256, 0, stream>>>(w1, w1T, 512, 2048);
  transp<<<dim3(16, 64), 256, 0, stream>>>(w2, w2T, 2048, 512);
  concat_bias<<<6, 256, 0, stream>>>(bq, bk, bv, bcat);

  ln_win<<<8192, 256, 0, stream>>>(hs, ln1g, ln1b, xw, 1);

  // fused QKV: (32768 x 512) @ (512 x 1536) -> qkv
  gemm_bt<256><<<dim3(128, 12), 512, 0, stream>>>(xw, wqkvT, bcat, qkv, nullptr, nullptr,
                                                  32768, 1536, 512, 0, 0);

  attn<<<dim3(512, 16), 64, 0, stream>>>(qkv, tbl, xw);

  // hid = hs + window_reverse(ctx @ Wo + bo)   (fp32, into d_out)
  gemm_bt<256><<<dim3(128, 4), 512, 0, stream>>>(xw, woT, bo, nullptr, hid, hs,
                                                 32768, 512, 512, 1, 0);

  // LN2(hid) -> qb (bf16)
  ln_win<<<8192, 256, 0, stream>>>(hid, ln2g, ln2b, qb, 0);

  for (int ch = 0; ch < 2; ++ch) {
    gemm_bt<256><<<dim3(64, 16), 512, 0, stream>>>(qb + (size_t)ch * 16384 * 512, w1T, b1, kb,
                                                   nullptr, nullptr, 16384, 2048, 512, 2, 0);
    // out = hid + y1 @ w2T + b2  (fp32, in-place RMW on d_out)
    gemm_bt<128><<<dim3(128, 4), 256, 0, stream>>>(kb, w2T, b2, nullptr, out, hid,
                                                   16384, 512, 2048, 3, ch * 16384);
  }
}

// Round 5
// 606.675 us; speedup vs baseline: 1.2118x; 1.0735x over previous
//
#include <hip/hip_runtime.h>

typedef unsigned short u16;
typedef __attribute__((ext_vector_type(8))) short short8;
typedef __attribute__((ext_vector_type(4))) float f32x4;

#define SHIFT_ 4

__device__ __forceinline__ float bf2f(u16 u) {
  unsigned x = ((unsigned)u) << 16;
  return __builtin_bit_cast(float, x);
}
__device__ __forceinline__ u16 f2bf(float f) {
  unsigned u = __builtin_bit_cast(unsigned, f);
  u += 0x7fffu + ((u >> 16) & 1u);
  return (u16)(u >> 16);
}
__device__ __forceinline__ short8 ld8(const u16* p) {
  return *(const short8*)p;
}
__device__ __forceinline__ void gld16(const void* g, void* l) {
  __builtin_amdgcn_global_load_lds(
      (const __attribute__((address_space(1))) unsigned int*)g,
      (__attribute__((address_space(3))) unsigned int*)l, 16, 0, 0);
}
__device__ __forceinline__ float gelu_t(float x) {
  float u = 0.7978845608028654f * (x + 0.044715f * x * x * x);
  float e = __expf(-2.f * fabsf(u));
  float th = (1.f - e) / (1.f + e);
  th = u < 0.f ? -th : th;
  return 0.5f * x * (1.f + th);
}

// ---------------- transpose + fp32->bf16 convert (R x C fp32 -> C x R bf16) --
__global__ void transp(const float* __restrict__ in, u16* __restrict__ out, int R, int C) {
  __shared__ u16 t[32][33];
  int tx = threadIdx.x & 31, ty = threadIdx.x >> 5;
  int c0 = blockIdx.x * 32, r0 = blockIdx.y * 32;
#pragma unroll
  for (int i = 0; i < 4; i++)
    t[ty + i * 8][tx] = f2bf(in[(size_t)(r0 + ty + i * 8) * C + c0 + tx]);
  __syncthreads();
#pragma unroll
  for (int i = 0; i < 4; i++)
    out[(size_t)(c0 + ty + i * 8) * R + r0 + tx] = t[tx][ty + i * 8];
}

__global__ void concat_bias(const float* __restrict__ a, const float* __restrict__ b,
                            const float* __restrict__ c, float* __restrict__ o) {
  int i = blockIdx.x * 256 + threadIdx.x;
  if (i < 512) o[i] = a[i];
  else if (i < 1024) o[i] = b[i - 512];
  else if (i < 1536) o[i] = c[i - 1024];
}

// ---------------- LayerNorm fp32 -> bf16 (optionally fused shift+window) -----
__global__ void ln_win(const float* __restrict__ hid, const float* __restrict__ g,
                       const float* __restrict__ b, u16* __restrict__ out, int windowed) {
  int wv = threadIdx.x >> 6, lane = threadIdx.x & 63;
  int tokid = blockIdx.x * 4 + wv;
  size_t src;
  if (windowed) {
    int t = tokid & 63, w = tokid >> 6;
    int winin = w & 63, bb = w >> 6;
    int r = ((winin >> 3) * 8 + (t >> 3) + SHIFT_) & 63;
    int c = ((winin & 7) * 8 + (t & 7) + SHIFT_) & 63;
    src = ((size_t)bb * 4096 + r * 64 + c) * 512;
  } else {
    src = (size_t)tokid * 512;
  }
  f32x4 x0 = *(const f32x4*)(hid + src + lane * 8);
  f32x4 x1 = *(const f32x4*)(hid + src + lane * 8 + 4);
  float x[8];
#pragma unroll
  for (int e = 0; e < 4; e++) { x[e] = x0[e]; x[e + 4] = x1[e]; }
  float s = 0.f, s2 = 0.f;
#pragma unroll
  for (int e = 0; e < 8; e++) {
    s += x[e];
    s2 += x[e] * x[e];
  }
#pragma unroll
  for (int m = 1; m < 64; m <<= 1) {
    s += __shfl_xor(s, m);
    s2 += __shfl_xor(s2, m);
  }
  float mean = s * (1.f / 512.f);
  float var = s2 * (1.f / 512.f) - mean * mean;
  float rstd = rsqrtf(var + 1e-5f);
  u16 pack[8];
#pragma unroll
  for (int e = 0; e < 8; e++) {
    int c = lane * 8 + e;
    float y = (x[e] - mean) * rstd * g[c] + b[c];
    pack[e] = f2bf(y);
  }
  *(short8*)(out + (size_t)tokid * 512 + lane * 8) = *(const short8*)pack;
}

// ---------------- GEMM: C = A(MxK) @ Bt^T + bias, Bt is (N x K) bf16 --------
// Tile 256x128, BK=32, 512 threads (8 waves, each 64x64 out).
// Double-buffered LDS, ONE barrier per K-iter: DMA for tile k+1 issued right
// after the barrier that completes tile k, in flight during tile-k compute.
// epi 0: outb = bf16(val)
// epi 1: window-reverse+unshift: outf[b,l,n] = resf[b,l,n] + val   (fp32)
// epi 2: outb = bf16(gelu(val))
// epi 3: outf[(row_off+m)*512+n] = resf[..] + val  (fp32, outf may alias resf)
__global__ __launch_bounds__(512) void gemm_bt(
    const u16* __restrict__ A, const u16* __restrict__ Bt,
    const float* __restrict__ bias, u16* __restrict__ outb, float* __restrict__ outf,
    const float* __restrict__ resf, int M, int N, int K, int epi, int row_off) {
  constexpr int BUF = (256 + 128) * 32;  // u16 per buffer (A 8192 + B 4096)
  __shared__ __attribute__((aligned(16))) u16 Ls[2 * BUF];
  const int tid = threadIdx.x;
  const int wv = tid >> 6, lane = tid & 63;
  const int l15 = lane & 15, quad = lane >> 4;
  const int m0 = blockIdx.x * 256, n0 = blockIdx.y * 128;
  const int wm = (wv >> 1) * 64, wn = (wv & 1) * 64;

  const int arow = tid >> 2;           // 0..127
  const int acol = (tid & 3) * 8;
  const u16* gA = A + (size_t)(m0 + arow) * K + acol;
  const u16* gB = Bt + (size_t)(n0 + arow) * K + acol;
  const int lAoff = tid * 8;           // rows 0..127
  const int lA2off = 4096 + tid * 8;   // rows 128..255
  const int lBoff = 8192 + tid * 8;

  f32x4 zero4 = {0.f, 0.f, 0.f, 0.f};
  f32x4 acc[4][4];
#pragma unroll
  for (int i = 0; i < 4; i++)
#pragma unroll
    for (int j = 0; j < 4; j++) acc[i][j] = zero4;

  const int kiter = K >> 5;
  // prologue: stage tile 0 into buffer 0
  {
    u16* base = Ls;
    gld16(gA, base + lAoff);
    gld16(gA + (size_t)128 * K, base + lA2off);
    gld16(gB, base + lBoff);
  }
  int p = 0;
  for (int ko = 0; ko < kiter; ++ko) {
    __syncthreads();  // tile ko resident in buffer p
    if (ko + 1 < kiter) {
      u16* base = Ls + (p ^ 1) * BUF;
      const u16* a = gA + (ko + 1) * 32;
      gld16(a, base + lAoff);
      gld16(a + (size_t)128 * K, base + lA2off);
      gld16(gB + (ko + 1) * 32, base + lBoff);
    }
    const u16* Ab = Ls + p * BUF;
    const u16* Bb = Ab + 8192;
    short8 af[4], bfr[4];
#pragma unroll
    for (int mt = 0; mt < 4; mt++) af[mt] = ld8(Ab + (wm + mt * 16 + l15) * 32 + quad * 8);
#pragma unroll
    for (int nt = 0; nt < 4; nt++) bfr[nt] = ld8(Bb + (wn + nt * 16 + l15) * 32 + quad * 8);
#pragma unroll
    for (int mt = 0; mt < 4; mt++)
#pragma unroll
      for (int nt = 0; nt < 4; nt++)
        acc[mt][nt] = __builtin_amdgcn_mfma_f32_16x16x32_bf16(af[mt], bfr[nt], acc[mt][nt], 0, 0, 0);
    p ^= 1;
  }

  float bvv[4];
#pragma unroll
  for (int nt = 0; nt < 4; nt++) bvv[nt] = bias[n0 + wn + nt * 16 + l15];

#pragma unroll
  for (int mt = 0; mt < 4; mt++) {
#pragma unroll
    for (int rr = 0; rr < 4; rr++) {
      int gm = m0 + wm + mt * 16 + quad * 4 + rr;
      size_t rowbase;
      if (epi == 1) {
        int tok = gm & 63, winin = (gm >> 6) & 63, bb = gm >> 12;
        int sr = (winin >> 3) * 8 + (tok >> 3);
        int sc = (winin & 7) * 8 + (tok & 7);
        int fr = (sr + SHIFT_) & 63, fc = (sc + SHIFT_) & 63;
        rowbase = ((size_t)bb * 4096 + fr * 64 + fc) * 512;
      } else if (epi == 3) {
        rowbase = (size_t)(row_off + gm) * 512;
      } else {
        rowbase = (size_t)gm * N;
      }
#pragma unroll
      for (int nt = 0; nt < 4; nt++) {
        int gn = n0 + wn + nt * 16 + l15;
        float val = acc[mt][nt][rr] + bvv[nt];
        if (epi == 0) {
          outb[rowbase + gn] = f2bf(val);
        } else if (epi == 2) {
          outb[rowbase + gn] = f2bf(gelu_t(val));
        } else {
          size_t idx = rowbase + gn;
          outf[idx] = resf[idx] + val;
        }
      }
    }
  }
}

// ---------------- attention: one wave per (window, head) ----------------
// qkv: (32768 x 1536) bf16, row = token, cols [h*32 | +512 k | +1024 v]
__global__ __launch_bounds__(64) void attn(const u16* __restrict__ qkv,
                                           const float* __restrict__ tbl,
                                           u16* __restrict__ ctx) {
  __shared__ __attribute__((aligned(16))) u16 Pl[64 * 80];
  __shared__ __attribute__((aligned(16))) u16 Vt[32 * 72];  // V^T: [dim][token]
  __shared__ float tb[225];
  const int win = blockIdx.x, h = blockIdx.y;
  const int lane = threadIdx.x;
  const int l15 = lane & 15, quad = lane >> 4;

  for (int idx = lane; idx < 225; idx += 64) tb[idx] = tbl[idx * 16 + h];

  const size_t qbase = (size_t)win * 64 * 1536 + h * 32;
  const size_t vbase = qbase + 1024;

  // stage V transposed via coalesced b128 loads
#pragma unroll
  for (int rnd = 0; rnd < 4; rnd++) {
    int t = rnd * 16 + (lane >> 2);
    int c = (lane & 3) * 8;
    short8 vrow = ld8(qkv + vbase + (size_t)t * 1536 + c);
#pragma unroll
    for (int j = 0; j < 8; j++) Vt[(c + j) * 72 + t] = (u16)vrow[j];
  }

  short8 aq[4], bkf[4];
#pragma unroll
  for (int mt = 0; mt < 4; mt++)
    aq[mt] = ld8(qkv + qbase + (size_t)(mt * 16 + l15) * 1536 + quad * 8);
#pragma unroll
  for (int nt = 0; nt < 4; nt++)
    bkf[nt] = ld8(qkv + qbase + 512 + (size_t)(nt * 16 + l15) * 1536 + quad * 8);

  f32x4 zero4 = {0.f, 0.f, 0.f, 0.f};
  f32x4 s[4][4];
#pragma unroll
  for (int i = 0; i < 4; i++)
#pragma unroll
    for (int j = 0; j < 4; j++) s[i][j] = zero4;
#pragma unroll
  for (int mt = 0; mt < 4; mt++)
#pragma unroll
    for (int nt = 0; nt < 4; nt++)
      s[mt][nt] = __builtin_amdgcn_mfma_f32_16x16x32_bf16(aq[mt], bkf[nt], s[mt][nt], 0, 0, 0);

  __syncthreads();  // tb + Vt ready

  const int winin = win & 63;
  const int wrow0 = (winin >> 3) * 8, wcol0 = (winin & 7) * 8;
  int valc[4], ci[4], cj[4];
#pragma unroll
  for (int nt = 0; nt < 4; nt++) {
    int ct = nt * 16 + l15;
    ci[nt] = ct >> 3;
    cj[nt] = ct & 7;
    int rr_ = wrow0 + ci[nt], cc_ = wcol0 + cj[nt];
    valc[nt] = 3 * (rr_ < 56 ? 0 : (rr_ < 60 ? 1 : 2)) + (cc_ < 56 ? 0 : (cc_ < 60 ? 1 : 2));
  }
  const float scale = 0.17677669529663687f;  // 1/sqrt(32)
#pragma unroll
  for (int mt = 0; mt < 4; mt++) {
#pragma unroll
    for (int rr = 0; rr < 4; rr++) {
      int rt = mt * 16 + quad * 4 + rr;
      int i1 = rt >> 3, j1 = rt & 7;
      int rrow = wrow0 + i1, rcol = wcol0 + j1;
      int valr = 3 * (rrow < 56 ? 0 : (rrow < 60 ? 1 : 2)) + (rcol < 56 ? 0 : (rcol < 60 ? 1 : 2));
      float sv[4];
      float sum = 0.f;
      // scores are O(+-10): exp without max-subtraction is safe in fp32
#pragma unroll
      for (int nt = 0; nt < 4; nt++) {
        int idx = (i1 - ci[nt] + 7) * 15 + (j1 - cj[nt] + 7);
        float e = s[mt][nt][rr] * scale + tb[idx] + (valr == valc[nt] ? 0.f : -100.f);
        sv[nt] = __expf(e);
        sum += sv[nt];
      }
#pragma unroll
      for (int m = 1; m < 16; m <<= 1) sum += __shfl_xor(sum, m);
      float inv = 1.f / sum;
#pragma unroll
      for (int nt = 0; nt < 4; nt++) Pl[rt * 80 + nt * 16 + l15] = f2bf(sv[nt] * inv);
    }
  }
  __syncthreads();

  // O = P(64x64) @ V(64x32), V^T from LDS
  f32x4 o[4][2];
#pragma unroll
  for (int i = 0; i < 4; i++)
#pragma unroll
    for (int j = 0; j < 2; j++) o[i][j] = zero4;
#pragma unroll
  for (int kk = 0; kk < 2; kk++) {
    short8 bv2[2];
#pragma unroll
    for (int nt = 0; nt < 2; nt++)
      bv2[nt] = ld8(Vt + (nt * 16 + l15) * 72 + kk * 32 + quad * 8);
#pragma unroll
    for (int mt = 0; mt < 4; mt++) {
      short8 ap = ld8(Pl + (mt * 16 + l15) * 80 + kk * 32 + quad * 8);
#pragma unroll
      for (int nt = 0; nt < 2; nt++)
        o[mt][nt] = __builtin_amdgcn_mfma_f32_16x16x32_bf16(ap, bv2[nt], o[mt][nt], 0, 0, 0);
    }
  }
  const size_t cbase = (size_t)win * 64 * 512 + h * 32;
#pragma unroll
  for (int mt = 0; mt < 4; mt++)
#pragma unroll
    for (int rr = 0; rr < 4; rr++) {
      int rt = mt * 16 + quad * 4 + rr;
#pragma unroll
      for (int nt = 0; nt < 2; nt++)
        ctx[cbase + (size_t)rt * 512 + nt * 16 + l15] = f2bf(o[mt][nt][rr]);
    }
}

extern "C" void kernel_launch(void* const* d_in, const int* in_sizes, int n_in,
                              void* d_out, int out_size, void* d_ws, size_t ws_size,
                              hipStream_t stream) {
  const float* hs   = (const float*)d_in[0];
  const float* ln1g = (const float*)d_in[1];
  const float* ln1b = (const float*)d_in[2];
  const float* wq   = (const float*)d_in[3];
  const float* bq   = (const float*)d_in[4];
  const float* wk   = (const float*)d_in[5];
  const float* bk   = (const float*)d_in[6];
  const float* wvp  = (const float*)d_in[7];
  const float* bv   = (const float*)d_in[8];
  const float* tbl  = (const float*)d_in[9];
  const float* wo   = (const float*)d_in[10];
  const float* bo   = (const float*)d_in[11];
  const float* ln2g = (const float*)d_in[12];
  const float* ln2b = (const float*)d_in[13];
  const float* w1   = (const float*)d_in[14];
  const float* b1   = (const float*)d_in[15];
  const float* w2   = (const float*)d_in[16];
  const float* b2   = (const float*)d_in[17];
  float* out = (float*)d_out;
  u16* ws = (u16*)d_ws;

  const size_t S = (size_t)32768 * 512;
  u16* xw   = ws;          // LN1 windowed out (bf16); later ctx
  u16* qkv  = ws + S;      // fused QKV out (32768 x 1536 bf16), spans 3S
  u16* qb   = ws + S;      // after attn: reused as LN2 out (S)
  u16* kb   = ws + 2 * S;  // after attn: y1 chunk (2S u16)
  u16* wt   = ws + 4 * S;  // transposed weights (bf16)
  u16* wqkvT = wt;         // 1536 x 512 (wq^T | wk^T | wv^T rows)
  u16* woT  = wt + 786432;
  u16* w1T  = wt + 1048576;
  u16* w2T  = wt + 2097152;
  float* bcat = (float*)(wt + 3145728);  // 1536 fp32
  float* hid = out;        // residual stream lives in d_out (fp32)

  transp<<<dim3(16, 16), 256, 0, stream>>>(wq, wqkvT, 512, 512);
  transp<<<dim3(16, 16), 256, 0, stream>>>(wk, wqkvT + 262144, 512, 512);
  transp<<<dim3(16, 16), 256, 0, stream>>>(wvp, wqkvT + 524288, 512, 512);
  transp<<<dim3(16, 16), 256, 0, stream>>>(wo, woT, 512, 512);
  transp<<<dim3(64, 16), 256, 0, stream>>>(w1, w1T, 512, 2048);
  transp<<<dim3(16, 64), 256, 0, stream>>>(w2, w2T, 2048, 512);
  concat_bias<<<6, 256, 0, stream>>>(bq, bk, bv, bcat);

  ln_win<<<8192, 256, 0, stream>>>(hs, ln1g, ln1b, xw, 1);

  // fused QKV: (32768 x 512) @ (512 x 1536) -> qkv
  gemm_bt<<<dim3(128, 12), 512, 0, stream>>>(xw, wqkvT, bcat, qkv, nullptr, nullptr,
                                             32768, 1536, 512, 0, 0);

  attn<<<dim3(512, 16), 64, 0, stream>>>(qkv, tbl, xw);

  // hid = hs + window_reverse(ctx @ Wo + bo)   (fp32, into d_out)
  gemm_bt<<<dim3(128, 4), 512, 0, stream>>>(xw, woT, bo, nullptr, hid, hs,
                                            32768, 512, 512, 1, 0);

  // LN2(hid) -> qb (bf16)
  ln_win<<<8192, 256, 0, stream>>>(hid, ln2g, ln2b, qb, 0);

  for (int ch = 0; ch < 2; ++ch) {
    gemm_bt<<<dim3(64, 16), 512, 0, stream>>>(qb + (size_t)ch * 16384 * 512, w1T, b1, kb,
                                              nullptr, nullptr, 16384, 2048, 512, 2, 0);
    // out = hid + y1 @ w2T + b2  (fp32, in-place RMW on d_out)
    gemm_bt<<<dim3(64, 4), 512, 0, stream>>>(kb, w2T, b2, nullptr, out, hid,
                                             16384, 512, 2048, 3, ch * 16384);
  }
}

// Round 6
// 570.707 us; speedup vs baseline: 1.2882x; 1.0630x over previous
//
#include <hip/hip_runtime.h>

typedef unsigned short u16;
typedef __attribute__((ext_vector_type(8))) short short8;
typedef __attribute__((ext_vector_type(4))) float f32x4;

#define SHIFT_ 4

__device__ __forceinline__ float bf2f(u16 u) {
  unsigned x = ((unsigned)u) << 16;
  return __builtin_bit_cast(float, x);
}
__device__ __forceinline__ u16 f2bf(float f) {
  unsigned u = __builtin_bit_cast(unsigned, f);
  u += 0x7fffu + ((u >> 16) & 1u);
  return (u16)(u >> 16);
}
__device__ __forceinline__ short8 ld8(const u16* p) {
  return *(const short8*)p;
}
__device__ __forceinline__ void gld16(const void* g, void* l) {
  __builtin_amdgcn_global_load_lds(
      (const __attribute__((address_space(1))) unsigned int*)g,
      (__attribute__((address_space(3))) unsigned int*)l, 16, 0, 0);
}
__device__ __forceinline__ float gelu_t(float x) {
  float u = 0.7978845608028654f * (x + 0.044715f * x * x * x);
  float e = __expf(-2.f * fabsf(u));
  float th = (1.f - e) / (1.f + e);
  th = u < 0.f ? -th : th;
  return 0.5f * x * (1.f + th);
}

// ---------------- transpose + fp32->bf16 convert (R x C fp32 -> C x R bf16) --
__global__ void transp(const float* __restrict__ in, u16* __restrict__ out, int R, int C) {
  __shared__ u16 t[32][33];
  int tx = threadIdx.x & 31, ty = threadIdx.x >> 5;
  int c0 = blockIdx.x * 32, r0 = blockIdx.y * 32;
#pragma unroll
  for (int i = 0; i < 4; i++)
    t[ty + i * 8][tx] = f2bf(in[(size_t)(r0 + ty + i * 8) * C + c0 + tx]);
  __syncthreads();
#pragma unroll
  for (int i = 0; i < 4; i++)
    out[(size_t)(c0 + ty + i * 8) * R + r0 + tx] = t[tx][ty + i * 8];
}

__global__ void concat_bias(const float* __restrict__ a, const float* __restrict__ b,
                            const float* __restrict__ c, float* __restrict__ o) {
  int i = blockIdx.x * 256 + threadIdx.x;
  if (i < 512) o[i] = a[i];
  else if (i < 1024) o[i] = b[i - 512];
  else if (i < 1536) o[i] = c[i - 1024];
}

// ---------------- LayerNorm fp32 -> bf16 (optionally fused shift+window) -----
__global__ void ln_win(const float* __restrict__ hid, const float* __restrict__ g,
                       const float* __restrict__ b, u16* __restrict__ out, int windowed) {
  int wv = threadIdx.x >> 6, lane = threadIdx.x & 63;
  int tokid = blockIdx.x * 4 + wv;
  size_t src;
  if (windowed) {
    int t = tokid & 63, w = tokid >> 6;
    int winin = w & 63, bb = w >> 6;
    int r = ((winin >> 3) * 8 + (t >> 3) + SHIFT_) & 63;
    int c = ((winin & 7) * 8 + (t & 7) + SHIFT_) & 63;
    src = ((size_t)bb * 4096 + r * 64 + c) * 512;
  } else {
    src = (size_t)tokid * 512;
  }
  f32x4 x0 = *(const f32x4*)(hid + src + lane * 8);
  f32x4 x1 = *(const f32x4*)(hid + src + lane * 8 + 4);
  float x[8];
#pragma unroll
  for (int e = 0; e < 4; e++) { x[e] = x0[e]; x[e + 4] = x1[e]; }
  float s = 0.f, s2 = 0.f;
#pragma unroll
  for (int e = 0; e < 8; e++) {
    s += x[e];
    s2 += x[e] * x[e];
  }
#pragma unroll
  for (int m = 1; m < 64; m <<= 1) {
    s += __shfl_xor(s, m);
    s2 += __shfl_xor(s2, m);
  }
  float mean = s * (1.f / 512.f);
  float var = s2 * (1.f / 512.f) - mean * mean;
  float rstd = rsqrtf(var + 1e-5f);
  u16 pack[8];
#pragma unroll
  for (int e = 0; e < 8; e++) {
    int c = lane * 8 + e;
    float y = (x[e] - mean) * rstd * g[c] + b[c];
    pack[e] = f2bf(y);
  }
  *(short8*)(out + (size_t)tokid * 512 + lane * 8) = *(const short8*)pack;
}

// ---------------- GEMM: C = A(MxK) @ Bt^T + bias, Bt is (N x K) bf16 --------
// Tile 256x128, BK=32, 512 threads (8 waves, 64x64 each). Double-buffered LDS,
// one barrier per K-iter. LDS is bank-swizzled: slot(row,c8') with
// c8' = (c8 + (row>>1)) & 3  -> frag ds_read_b128 is 2-way (free) instead of
// 8-way. Staging source column rotated to match (same 64B segment per 4 lanes,
// coalescing unchanged).
// epi 0: head-major QKV: out[(part*16+h)*32768 + m][d], part=gn>>9,h,d from gn
// epi 1: window-reverse+unshift: outf[b,l,n] = resf[b,l,n] + val   (fp32)
// epi 2: outb = bf16(gelu(val))
// epi 3: outf[m*512+n] = resf[..] + val  (fp32, outf may alias resf)
__global__ __launch_bounds__(512) void gemm_bt(
    const u16* __restrict__ A, const u16* __restrict__ Bt,
    const float* __restrict__ bias, u16* __restrict__ outb, float* __restrict__ outf,
    const float* __restrict__ resf, int M, int N, int K, int epi) {
  constexpr int BUF = (256 + 128) * 32;  // u16 per buffer (A 8192 + B 4096)
  __shared__ __attribute__((aligned(16))) u16 Ls[2 * BUF];
  const int tid = threadIdx.x;
  const int wv = tid >> 6, lane = tid & 63;
  const int l15 = lane & 15, quad = lane >> 4;
  const int m0 = blockIdx.x * 256, n0 = blockIdx.y * 128;
  const int wm = (wv >> 1) * 64, wn = (wv & 1) * 64;

  const int arow = tid >> 2;  // 0..127
  // swizzled source col-group: c8 = ((tid&3) - (row>>1)) & 3, row = tid>>2
  const int acol = (((tid & 3) - (tid >> 3)) & 3) * 8;
  const u16* gA = A + (size_t)(m0 + arow) * K + acol;
  const u16* gB = Bt + (size_t)(n0 + arow) * K + acol;
  const int lAoff = tid * 8;           // rows 0..127
  const int lA2off = 4096 + tid * 8;   // rows 128..255 (same swizzle: 128>>1 ≡ 0 mod 4)
  const int lBoff = 8192 + tid * 8;

  f32x4 zero4 = {0.f, 0.f, 0.f, 0.f};
  f32x4 acc[4][4];
#pragma unroll
  for (int i = 0; i < 4; i++)
#pragma unroll
    for (int j = 0; j < 4; j++) acc[i][j] = zero4;

  const int kiter = K >> 5;
  {
    u16* base = Ls;
    gld16(gA, base + lAoff);
    gld16(gA + (size_t)128 * K, base + lA2off);
    gld16(gB, base + lBoff);
  }
  int p = 0;
  for (int ko = 0; ko < kiter; ++ko) {
    __syncthreads();  // tile ko resident in buffer p
    if (ko + 1 < kiter) {
      u16* base = Ls + (p ^ 1) * BUF;
      const u16* a = gA + (ko + 1) * 32;
      gld16(a, base + lAoff);
      gld16(a + (size_t)128 * K, base + lA2off);
      gld16(gB + (ko + 1) * 32, base + lBoff);
    }
    const u16* Ab = Ls + p * BUF;
    const u16* Bb = Ab + 8192;
    short8 af[4], bfr[4];
#pragma unroll
    for (int mt = 0; mt < 4; mt++) {
      int row = wm + mt * 16 + l15;
      af[mt] = ld8(Ab + (row * 4 + ((quad + (row >> 1)) & 3)) * 8);
    }
#pragma unroll
    for (int nt = 0; nt < 4; nt++) {
      int row = wn + nt * 16 + l15;
      bfr[nt] = ld8(Bb + (row * 4 + ((quad + (row >> 1)) & 3)) * 8);
    }
#pragma unroll
    for (int mt = 0; mt < 4; mt++)
#pragma unroll
      for (int nt = 0; nt < 4; nt++)
        acc[mt][nt] = __builtin_amdgcn_mfma_f32_16x16x32_bf16(af[mt], bfr[nt], acc[mt][nt], 0, 0, 0);
    p ^= 1;
  }

  float bvv[4];
#pragma unroll
  for (int nt = 0; nt < 4; nt++) bvv[nt] = bias[n0 + wn + nt * 16 + l15];

#pragma unroll
  for (int mt = 0; mt < 4; mt++) {
#pragma unroll
    for (int rr = 0; rr < 4; rr++) {
      int gm = m0 + wm + mt * 16 + quad * 4 + rr;
      size_t rowbase = 0;
      if (epi == 1) {
        int tok = gm & 63, winin = (gm >> 6) & 63, bb = gm >> 12;
        int sr = (winin >> 3) * 8 + (tok >> 3);
        int sc = (winin & 7) * 8 + (tok & 7);
        int fr = (sr + SHIFT_) & 63, fc = (sc + SHIFT_) & 63;
        rowbase = ((size_t)bb * 4096 + fr * 64 + fc) * 512;
      } else if (epi == 3) {
        rowbase = (size_t)gm * 512;
      } else if (epi == 2) {
        rowbase = (size_t)gm * N;
      }
#pragma unroll
      for (int nt = 0; nt < 4; nt++) {
        int gn = n0 + wn + nt * 16 + l15;
        float val = acc[mt][nt][rr] + bvv[nt];
        if (epi == 0) {
          int part = gn >> 9, hh = (gn >> 5) & 15, dd = gn & 31;
          size_t dst = (((size_t)(part * 16 + hh) * 32768) + gm) * 32 + dd;
          outb[dst] = f2bf(val);
        } else if (epi == 2) {
          outb[rowbase + gn] = f2bf(gelu_t(val));
        } else {
          size_t idx = rowbase + gn;
          outf[idx] = resf[idx] + val;
        }
      }
    }
  }
}

// ---------------- attention: one wave per (window, head) ----------------
// q/k/v: head-major [h][32768][32] bf16 (contiguous 64x32 tile per win,h)
__global__ __launch_bounds__(64) void attn(const u16* __restrict__ q, const u16* __restrict__ k,
                                           const u16* __restrict__ v, const float* __restrict__ tbl,
                                           u16* __restrict__ ctx) {
  __shared__ __attribute__((aligned(16))) u16 Pl[64 * 80];
  __shared__ __attribute__((aligned(16))) u16 Vt[32 * 72];  // V^T: [dim][token]
  __shared__ float tb[225];
  const int win = blockIdx.x, h = blockIdx.y;
  const int lane = threadIdx.x;
  const int l15 = lane & 15, quad = lane >> 4;

  for (int idx = lane; idx < 225; idx += 64) tb[idx] = tbl[idx * 16 + h];

  const size_t tilebase = ((size_t)h * 32768 + win * 64) * 32;
  const u16* qh = q + tilebase;
  const u16* kh = k + tilebase;
  const u16* vh = v + tilebase;

  // stage V transposed via fully-coalesced b128 loads
#pragma unroll
  for (int rnd = 0; rnd < 4; rnd++) {
    int t = rnd * 16 + (lane >> 2);
    int c = (lane & 3) * 8;
    short8 vrow = ld8(vh + t * 32 + c);
#pragma unroll
    for (int j = 0; j < 8; j++) Vt[(c + j) * 72 + t] = (u16)vrow[j];
  }

  short8 aq[4], bkf[4];
#pragma unroll
  for (int mt = 0; mt < 4; mt++) aq[mt] = ld8(qh + (mt * 16 + l15) * 32 + quad * 8);
#pragma unroll
  for (int nt = 0; nt < 4; nt++) bkf[nt] = ld8(kh + (nt * 16 + l15) * 32 + quad * 8);

  f32x4 zero4 = {0.f, 0.f, 0.f, 0.f};
  f32x4 s[4][4];
#pragma unroll
  for (int i = 0; i < 4; i++)
#pragma unroll
    for (int j = 0; j < 4; j++) s[i][j] = zero4;
#pragma unroll
  for (int mt = 0; mt < 4; mt++)
#pragma unroll
    for (int nt = 0; nt < 4; nt++)
      s[mt][nt] = __builtin_amdgcn_mfma_f32_16x16x32_bf16(aq[mt], bkf[nt], s[mt][nt], 0, 0, 0);

  __syncthreads();  // tb + Vt ready

  const int winin = win & 63;
  const int wrow0 = (winin >> 3) * 8, wcol0 = (winin & 7) * 8;
  int valc[4], ci[4], cj[4];
#pragma unroll
  for (int nt = 0; nt < 4; nt++) {
    int ct = nt * 16 + l15;
    ci[nt] = ct >> 3;
    cj[nt] = ct & 7;
    int rr_ = wrow0 + ci[nt], cc_ = wcol0 + cj[nt];
    valc[nt] = 3 * (rr_ < 56 ? 0 : (rr_ < 60 ? 1 : 2)) + (cc_ < 56 ? 0 : (cc_ < 60 ? 1 : 2));
  }
  const float scale = 0.17677669529663687f;  // 1/sqrt(32)
#pragma unroll
  for (int mt = 0; mt < 4; mt++) {
#pragma unroll
    for (int rr = 0; rr < 4; rr++) {
      int rt = mt * 16 + quad * 4 + rr;
      int i1 = rt >> 3, j1 = rt & 7;
      int rrow = wrow0 + i1, rcol = wcol0 + j1;
      int valr = 3 * (rrow < 56 ? 0 : (rrow < 60 ? 1 : 2)) + (rcol < 56 ? 0 : (rcol < 60 ? 1 : 2));
      float sv[4];
      float sum = 0.f;
      // scores are O(+-10): exp without max-subtraction is safe in fp32
#pragma unroll
      for (int nt = 0; nt < 4; nt++) {
        int idx = (i1 - ci[nt] + 7) * 15 + (j1 - cj[nt] + 7);
        float e = s[mt][nt][rr] * scale + tb[idx] + (valr == valc[nt] ? 0.f : -100.f);
        sv[nt] = __expf(e);
        sum += sv[nt];
      }
#pragma unroll
      for (int m = 1; m < 16; m <<= 1) sum += __shfl_xor(sum, m);
      float inv = 1.f / sum;
#pragma unroll
      for (int nt = 0; nt < 4; nt++) Pl[rt * 80 + nt * 16 + l15] = f2bf(sv[nt] * inv);
    }
  }
  __syncthreads();

  // O = P(64x64) @ V(64x32), V^T from LDS
  f32x4 o[4][2];
#pragma unroll
  for (int i = 0; i < 4; i++)
#pragma unroll
    for (int j = 0; j < 2; j++) o[i][j] = zero4;
#pragma unroll
  for (int kk = 0; kk < 2; kk++) {
    short8 bv2[2];
#pragma unroll
    for (int nt = 0; nt < 2; nt++)
      bv2[nt] = ld8(Vt + (nt * 16 + l15) * 72 + kk * 32 + quad * 8);
#pragma unroll
    for (int mt = 0; mt < 4; mt++) {
      short8 ap = ld8(Pl + (mt * 16 + l15) * 80 + kk * 32 + quad * 8);
#pragma unroll
      for (int nt = 0; nt < 2; nt++)
        o[mt][nt] = __builtin_amdgcn_mfma_f32_16x16x32_bf16(ap, bv2[nt], o[mt][nt], 0, 0, 0);
    }
  }
  const size_t cbase = (size_t)win * 64 * 512 + h * 32;
#pragma unroll
  for (int mt = 0; mt < 4; mt++)
#pragma unroll
    for (int rr = 0; rr < 4; rr++) {
      int rt = mt * 16 + quad * 4 + rr;
#pragma unroll
      for (int nt = 0; nt < 2; nt++)
        ctx[cbase + (size_t)rt * 512 + nt * 16 + l15] = f2bf(o[mt][nt][rr]);
    }
}

extern "C" void kernel_launch(void* const* d_in, const int* in_sizes, int n_in,
                              void* d_out, int out_size, void* d_ws, size_t ws_size,
                              hipStream_t stream) {
  const float* hs   = (const float*)d_in[0];
  const float* ln1g = (const float*)d_in[1];
  const float* ln1b = (const float*)d_in[2];
  const float* wq   = (const float*)d_in[3];
  const float* bq   = (const float*)d_in[4];
  const float* wk   = (const float*)d_in[5];
  const float* bk   = (const float*)d_in[6];
  const float* wvp  = (const float*)d_in[7];
  const float* bv   = (const float*)d_in[8];
  const float* tbl  = (const float*)d_in[9];
  const float* wo   = (const float*)d_in[10];
  const float* bo   = (const float*)d_in[11];
  const float* ln2g = (const float*)d_in[12];
  const float* ln2b = (const float*)d_in[13];
  const float* w1   = (const float*)d_in[14];
  const float* b1   = (const float*)d_in[15];
  const float* w2   = (const float*)d_in[16];
  const float* b2   = (const float*)d_in[17];
  float* out = (float*)d_out;
  u16* ws = (u16*)d_ws;

  const size_t S = (size_t)32768 * 512;
  u16* xw   = ws;          // LN1 out / ctx / LN2 out (bf16, S)
  u16* qb   = ws + S;      // Q head-major [16][32768][32]
  u16* kb   = ws + 2 * S;  // K head-major
  u16* vb   = ws + 3 * S;  // V head-major
  u16* y1   = ws + S;      // MLP intermediate (32768 x 2048 bf16, 4S) after attn
  u16* wt   = ws + 5 * S;  // transposed weights (bf16)
  u16* wqkvT = wt;         // 1536 x 512 (wq^T | wk^T | wv^T rows)
  u16* woT  = wt + 786432;
  u16* w1T  = wt + 1048576;
  u16* w2T  = wt + 2097152;
  float* bcat = (float*)(wt + 3145728);  // 1536 fp32
  float* hid = out;        // residual stream lives in d_out (fp32)

  transp<<<dim3(16, 16), 256, 0, stream>>>(wq, wqkvT, 512, 512);
  transp<<<dim3(16, 16), 256, 0, stream>>>(wk, wqkvT + 262144, 512, 512);
  transp<<<dim3(16, 16), 256, 0, stream>>>(wvp, wqkvT + 524288, 512, 512);
  transp<<<dim3(16, 16), 256, 0, stream>>>(wo, woT, 512, 512);
  transp<<<dim3(64, 16), 256, 0, stream>>>(w1, w1T, 512, 2048);
  transp<<<dim3(16, 64), 256, 0, stream>>>(w2, w2T, 2048, 512);
  concat_bias<<<6, 256, 0, stream>>>(bq, bk, bv, bcat);

  ln_win<<<8192, 256, 0, stream>>>(hs, ln1g, ln1b, xw, 1);

  // fused QKV: (32768 x 512) @ (512 x 1536) -> head-major Q/K/V at ws+S
  gemm_bt<<<dim3(128, 12), 512, 0, stream>>>(xw, wqkvT, bcat, qb, nullptr, nullptr,
                                             32768, 1536, 512, 0);

  attn<<<dim3(512, 16), 64, 0, stream>>>(qb, kb, vb, tbl, xw);

  // hid = hs + window_reverse(ctx @ Wo + bo)   (fp32, into d_out)
  gemm_bt<<<dim3(128, 4), 512, 0, stream>>>(xw, woT, bo, nullptr, hid, hs,
                                            32768, 512, 512, 1);

  // LN2(hid) -> xw (bf16)
  ln_win<<<8192, 256, 0, stream>>>(hid, ln2g, ln2b, xw, 0);

  // y1 = gelu(LN2 @ w1 + b1), full M
  gemm_bt<<<dim3(128, 16), 512, 0, stream>>>(xw, w1T, b1, y1, nullptr, nullptr,
                                             32768, 2048, 512, 2);
  // out = hid + y1 @ w2T + b2  (fp32, in-place RMW on d_out)
  gemm_bt<<<dim3(128, 4), 512, 0, stream>>>(y1, w2T, b2, nullptr, out, hid,
                                            32768, 512, 2048, 3);
}